// Round 8
// baseline (827.153 us; speedup 1.0000x reference)
//
#include <hip/hip_runtime.h>
#include <stdint.h>

// ManualLSTM: B=512, T=1024, D=64, U=128.
// R15: R14 with the spill bug fixed -- launch_bounds(1024, 4), not (1024, 8).
// R14 evidence: occupancy 87% (two 16-wave WGs DO co-reside) but the forced
// 8-waves/SIMD register budget spilled the consumer state (VGPR_Count 32,
// WRITE_SIZE 98.5MB of scratch) and cost 2x. R13 measured that (1024,4)
// naturally compiles this code to 64 VGPR -- which already PERMITS 8
// waves/SIMD in hardware; the min-waves arg only constrains the allocator.
// So: ROWS=1, NBLK=512, 2 WGs/CU (LDS 2x68KB=136KB <= 160KB), 64-VGPR code.
// Two independent chains per CU overlap barrier/ds-latency/activation stalls
// against each other's MFMA bursts.
//  - waves 0-7 = consumers, each owns 16 u-cols: 4 scaled fp8 MFMAs/step,
//    burst-then-activate, log2e-folded activations (R9-verified math).
//  - waves 8-15 = producers: 1 u-subtile x 4 gates, 1 xproj tile per odd step.
//  - ROWS=1 duplication (R12/R14-verified): both M-halves carry the same
//    batch row; only quad 0 writes out.
// Gx race-free: consumers read Gx[g&1], producers write Gx[(g+1)&1].
// A1 (h fp8) step-parity dbuf; sync_lds drains lgkm only (x loads in flight).

typedef __attribute__((ext_vector_type(8))) short short8;
typedef __attribute__((ext_vector_type(4))) float floatx4;
typedef __attribute__((ext_vector_type(4))) int   intx4;
typedef __attribute__((ext_vector_type(8))) int   intx8;

#define B_SZ   512
#define T_SZ   1024
#define D_SZ   64
#define U_SZ   128
#define ROWS   1
#define NBLK   (B_SZ / ROWS)   // 512 blocks -> 2 WGs/CU
#define NTHR   1024            // 16 waves: 0-7 consumers, 8-15 producers
#define A1STRB 160             // h row stride in BYTES (128 fp8 + 32 pad)
#define GXSTR  524             // Gx row stride in fp32
#define L2E    1.4426950408889634f

__device__ __forceinline__ short f2bf(float f) {
    uint32_t u = __builtin_bit_cast(uint32_t, f);
    uint32_t r = (u + 0x7fffu + ((u >> 16) & 1u)) >> 16;   // RNE
    return (short)r;
}
__device__ __forceinline__ int cvt2bf(float lo, float hi) {
    int r;
    asm("v_cvt_pk_bf16_f32 %0, %1, %2" : "=v"(r) : "v"(lo), "v"(hi));
    return r;
}
__device__ __forceinline__ short8 pk8(float4 a, float4 b) {
    intx4 t = {cvt2bf(a.x, a.y), cvt2bf(a.z, a.w), cvt2bf(b.x, b.y), cvt2bf(b.z, b.w)};
    return __builtin_bit_cast(short8, t);
}
// args pre-scaled by -L2E / +2*L2E (R9-verified helpers)
__device__ __forceinline__ float fsig2(float e) {   // sigmoid, e = -L2E*x
    return __builtin_amdgcn_rcpf(1.0f + __builtin_amdgcn_exp2f(e));
}
__device__ __forceinline__ float fth2(float e) {    // tanh, e = +2*L2E*x
    return 1.0f - 2.0f * __builtin_amdgcn_rcpf(1.0f + __builtin_amdgcn_exp2f(e));
}
__device__ __forceinline__ float ftanh(float x) {
    return 1.0f - 2.0f * __builtin_amdgcn_rcpf(1.0f + __builtin_amdgcn_exp2f(2.0f * L2E * x));
}
// barrier draining only LDS ops (NOT vmcnt -> producer global loads stay in flight)
__device__ __forceinline__ void sync_lds() {
    asm volatile("s_waitcnt lgkmcnt(0)\n\ts_barrier" ::: "memory");
}

__global__ __launch_bounds__(NTHR, 4) void lstm_persistent(
    const float* __restrict__ xin,
    const float* __restrict__ Wf, const float* __restrict__ Uf, const float* __restrict__ bfp,
    const float* __restrict__ Wi, const float* __restrict__ Ui, const float* __restrict__ bip,
    const float* __restrict__ Wc, const float* __restrict__ Uc, const float* __restrict__ bcp,
    const float* __restrict__ Wo, const float* __restrict__ Uo, const float* __restrict__ bop,
    float* __restrict__ out)
{
    __shared__ float Gx[2][16 * GXSTR];              // pre-scaled xproj, dbuf by group parity
    __shared__ __align__(8) char A1[2][2 * A1STRB];  // h fp8-e4m3, dbuf by step parity

    const int tid  = threadIdx.x;
    const int wave = tid >> 6;     // 0..15
    const int lane = tid & 63;
    const int quad = lane >> 4;    // 0..3
    const int nlo  = lane & 15;
    const int blk  = blockIdx.x;

    const float* Wg[4] = {Wf, Wi, Wc, Wo};
    const float* Ug[4] = {Uf, Ui, Uc, Uo};
    const float* Bg[4] = {bfp, bip, bcp, bop};
    const float scg[4] = {-L2E, -L2E, 2.0f * L2E, -L2E};

    if (wave < 8) {
        // ======================= CONSUMER (8 thin waves) =======================
        __builtin_amdgcn_s_setprio(1);   // chain waves are latency-critical
        const int  prow = quad >> 1;        // ROWS=1: rows 0/1 are dup copies
        const bool wr   = (quad & 1) == 0;  // quads 1,3 mirror 0,2
        const int  u_s  = 16 * wave + nlo;  // this wave's u-column

        // recurrent U as fp8 B-fragments (16 cols, 4 gates): byte j of dword d
        // -> k = quad*32 + 4d + j; col = nlo within the wave's 16-col tile.
        intx8 bU8[4];
#pragma unroll
        for (int gt = 0; gt < 4; ++gt)
#pragma unroll
            for (int d = 0; d < 8; ++d) {
                const int k0 = quad * 32 + d * 4;
                int pk = __builtin_amdgcn_cvt_pk_fp8_f32(
                    Ug[gt][(k0 + 0) * U_SZ + u_s], Ug[gt][(k0 + 1) * U_SZ + u_s], 0, 0);
                pk = __builtin_amdgcn_cvt_pk_fp8_f32(
                    Ug[gt][(k0 + 2) * U_SZ + u_s], Ug[gt][(k0 + 3) * U_SZ + u_s], pk, 1);
                bU8[gt][d] = pk;
            }
        float c_st = 0.0f;

        // zero both h buffers (h(0)=0); consumer tids are 0..511
        for (int i = tid; i < 2 * 2 * A1STRB; i += 512) ((char*)A1)[i] = 0;
        __syncthreads();

        for (int g = 0; g < 128; ++g) {
            const float* GxR = &Gx[g & 1][0];
#pragma unroll
            for (int j = 0; j < 8; ++j) {
                // ---- reads first: h fragment (2x b128) then xproj (b128) ----
                const char* ap = &A1[j & 1][(nlo >> 3) * A1STRB + quad * 32];
                intx4 alo = *(const intx4*)(ap);
                intx4 ahi = *(const intx4*)(ap + 16);
                floatx4 gx = *(const floatx4*)&GxR[(2 * j + prow) * GXSTR + 4 * u_s];
                intx8 a8 = {alo.x, alo.y, alo.z, alo.w, ahi.x, ahi.y, ahi.z, ahi.w};
                const floatx4 z = (floatx4){0.f, 0.f, 0.f, 0.f};

                // ---- 4 scaled fp8 MFMAs back-to-back (burst-then-activate) ----
                floatx4 acc[4];
#pragma unroll
                for (int gt = 0; gt < 4; ++gt)
                    acc[gt] = __builtin_amdgcn_mfma_scale_f32_16x16x128_f8f6f4(
                        a8, bU8[gt], z, 0, 0, 0, 0x7f7f7f7f, 0, 0x7f7f7f7f);

                // ---- log2e-folded activations (no ti-select needed) ----
                float fg = fsig2(__builtin_fmaf(acc[0][0], -L2E, gx[0]));
                float ig = fsig2(__builtin_fmaf(acc[1][0], -L2E, gx[1]));
                float ct = fth2(__builtin_fmaf(acc[2][0], 2.0f * L2E, gx[2]));
                float og = fsig2(__builtin_fmaf(acc[3][0], -L2E, gx[3]));

                float c = fg * c_st + ig * ct;
                float h = og * ftanh(c);
                c_st = c;

                if (g == 127 && j == 7) {
                    if (quad == 0) out[(size_t)blk * U_SZ + u_s] = h;
                } else if (wr) {
                    int pk = __builtin_amdgcn_cvt_pk_fp8_f32(h, h, 0, 0);
                    A1[(j & 1) ^ 1][prow * A1STRB + u_s] = (char)(pk & 0xff);
                }
                sync_lds();
            }
        }
    } else {
        // ======================= PRODUCER (8 waves) =======================
        // wave p owns u-subtile p x 4 gates = 4 N-tiles; 1 tile per odd step.
        // ROWS=1: both M-halves read the same batch row (duplication).
        const int p = wave - 8;
        const int t_off = nlo >> 1;    // A-frag row m=nlo -> (t_off, dup copy)
        const int uc    = 16 * p + nlo;

        // bW fragments for 4 tiles (one per gate), K=64 (2 kt) + bias.
        short8 bWp[4][2];
        float  bw[4];
#pragma unroll
        for (int gt = 0; gt < 4; ++gt) {
            bw[gt] = Bg[gt][uc];
#pragma unroll
            for (int kt = 0; kt < 2; ++kt)
#pragma unroll
                for (int jj = 0; jj < 8; ++jj) {
                    int k = kt * 32 + quad * 8 + jj;
                    bWp[gt][kt][jj] = f2bf(Wg[gt][k * U_SZ + uc]);
                }
        }

        const float* xg = xin + ((size_t)blk * T_SZ) * D_SZ + quad * 8;

        // ---- prologue: xproj(0) -> Gx[0]; xa = x(1); xq = x(2) in flight ----
        float4 p0 = *(const float4*)(xg + (size_t)t_off * D_SZ + 0);
        float4 p1 = *(const float4*)(xg + (size_t)t_off * D_SZ + 4);
        float4 p2 = *(const float4*)(xg + (size_t)t_off * D_SZ + 32);
        float4 p3 = *(const float4*)(xg + (size_t)t_off * D_SZ + 36);
        float4 q0 = *(const float4*)(xg + (size_t)(8 + t_off) * D_SZ + 0);
        float4 q1 = *(const float4*)(xg + (size_t)(8 + t_off) * D_SZ + 4);
        float4 q2 = *(const float4*)(xg + (size_t)(8 + t_off) * D_SZ + 32);
        float4 q3 = *(const float4*)(xg + (size_t)(8 + t_off) * D_SZ + 36);

        short8 xa0 = pk8(p0, p1);
        short8 xa1 = pk8(p2, p3);
#pragma unroll
        for (int gt = 0; gt < 4; ++gt) {
            floatx4 acc = (floatx4){0.f, 0.f, 0.f, 0.f};
            acc = __builtin_amdgcn_mfma_f32_16x16x32_bf16(xa0, bWp[gt][0], acc, 0, 0, 0);
            acc = __builtin_amdgcn_mfma_f32_16x16x32_bf16(xa1, bWp[gt][1], acc, 0, 0, 0);
#pragma unroll
            for (int r = 0; r < 4; ++r)
                Gx[0][(quad * 4 + r) * GXSTR + 4 * uc + gt] = (acc[r] + bw[gt]) * scg[gt];
        }
        // xa = x(1)
        xa0 = pk8(q0, q1);
        xa1 = pk8(q2, q3);
        // xq = x(2), in flight
        float4 xq0 = *(const float4*)(xg + (size_t)(16 + t_off) * D_SZ + 0);
        float4 xq1 = *(const float4*)(xg + (size_t)(16 + t_off) * D_SZ + 4);
        float4 xq2 = *(const float4*)(xg + (size_t)(16 + t_off) * D_SZ + 32);
        float4 xq3 = *(const float4*)(xg + (size_t)(16 + t_off) * D_SZ + 36);
        __syncthreads();

        short8 xn0 = xa0, xn1 = xa1;
        for (int g = 0; g < 128; ++g) {
            float* GxW = &Gx[(g + 1) & 1][0];
#pragma unroll
            for (int j = 0; j < 8; ++j) {
                if (j == 0 && g <= 125) {   // cvt xq -> x(g+2) frags
                    xn0 = pk8(xq0, xq1);
                    xn1 = pk8(xq2, xq3);
                }
                if (j == 2 && g <= 124) {   // issue loads of x(g+3)
                    const float* b = xg + (size_t)(8 * (g + 3) + t_off) * D_SZ;
                    xq0 = *(const float4*)(b + 0);
                    xq1 = *(const float4*)(b + 4);
                    xq2 = *(const float4*)(b + 32);
                    xq3 = *(const float4*)(b + 36);
                }
                if ((j & 1) && g < 127) {   // gate gt=j>>1 tile of xproj(g+1)
                    const int gt = j >> 1;
                    floatx4 acc = (floatx4){0.f, 0.f, 0.f, 0.f};
                    acc = __builtin_amdgcn_mfma_f32_16x16x32_bf16(xa0, bWp[gt][0], acc, 0, 0, 0);
                    acc = __builtin_amdgcn_mfma_f32_16x16x32_bf16(xa1, bWp[gt][1], acc, 0, 0, 0);
#pragma unroll
                    for (int r = 0; r < 4; ++r)
                        GxW[(quad * 4 + r) * GXSTR + 4 * uc + gt] = (acc[r] + bw[gt]) * scg[gt];
                }
                sync_lds();
            }
            xa0 = xn0; xa1 = xn1;
        }
    }
}

extern "C" void kernel_launch(void* const* d_in, const int* in_sizes, int n_in,
                              void* d_out, int out_size, void* d_ws, size_t ws_size,
                              hipStream_t stream) {
    (void)in_sizes; (void)n_in; (void)d_ws; (void)ws_size; (void)out_size;
    const float* xin = (const float*)d_in[0];
    const float* Wf  = (const float*)d_in[1];
    const float* Uf  = (const float*)d_in[2];
    const float* bf  = (const float*)d_in[3];
    const float* Wi  = (const float*)d_in[4];
    const float* Ui  = (const float*)d_in[5];
    const float* bi  = (const float*)d_in[6];
    const float* Wc  = (const float*)d_in[7];
    const float* Uc  = (const float*)d_in[8];
    const float* bc  = (const float*)d_in[9];
    const float* Wo  = (const float*)d_in[10];
    const float* Uo  = (const float*)d_in[11];
    const float* bo  = (const float*)d_in[12];
    float* out = (float*)d_out;

    hipLaunchKernelGGL(lstm_persistent, dim3(NBLK), dim3(NTHR), 0, stream,
                       xin, Wf, Uf, bf, Wi, Ui, bi, Wc, Uc, bc, Wo, Uo, bo, out);
}

// Round 10
// 509.173 us; speedup vs baseline: 1.6245x; 1.6245x over previous
//
#include <hip/hip_runtime.h>
#include <stdint.h>

// ManualLSTM: B=512, T=1024, D=64, U=128.
// R17 = R16 resubmitted verbatim (R9 bench round died on container
// acquisition -- "MI355X container failed twice" -- kernel never ran).
// R16: R13 base (best verified, 388us) + consumer tail diet + conflict kill.
//  1. gx-as-C: C/D row = quad*4+reg; all 4 regs of a quad are the SAME batch
//     row (row>>3 = quad>>1), so passing the gx floatx4 as C-in to all 4
//     MFMAs and reading acc[gt][gt] gives hU_gt + gx[gt] exactly. No zero-C
//     quad, no post-MFMA FMAs.
//  2. scg folded into quantized weights: bU8 = fp8(scg*U), bWp = bf16(scg*W),
//     bias = scg*b -> MFMA output IS the exp2 argument (scg = -L2E f/i/o,
//     +2*L2E for c).
//  3. Gate-major Gx [row][gt*128+u]: producer writes become lane-stride-1
//     (2-way = free; was stride-4 = 8-way conflict ~95 cyc/step); consumer
//     reads = 4x ds_read_b32, broadcast across quad pairs. GXSTR=524 keeps
//     quad rows on distinct bank offsets.
// Structure (R13): 256 blocks x 1024 thr, launch_bounds(1024,4).
//  - waves 0-7 consumers (prio1): 16 u-cols each, 4 scaled fp8 MFMAs/step,
//    burst-then-activate.
//  - waves 8-15 producers: 1 u-subtile x 4 gates, 1 xproj tile per odd step.
// Gx race-free: consumers read Gx[g&1], producers write Gx[(g+1)&1].
// A1 (h fp8) step-parity dbuf; sync_lds drains lgkm only (x loads in flight).

typedef __attribute__((ext_vector_type(8))) short short8;
typedef __attribute__((ext_vector_type(4))) float floatx4;
typedef __attribute__((ext_vector_type(4))) int   intx4;
typedef __attribute__((ext_vector_type(8))) int   intx8;

#define B_SZ   512
#define T_SZ   1024
#define D_SZ   64
#define U_SZ   128
#define ROWS   2
#define NBLK   (B_SZ / ROWS)   // 256 blocks, 1 per CU
#define NTHR   1024            // 16 waves: 0-7 consumers, 8-15 producers
#define A1STRB 160             // h row stride in BYTES (128 fp8 + 32 pad)
#define GXSTR  524             // Gx row stride in fp32 (512 data + 12 pad)
#define L2E    1.4426950408889634f

__device__ __forceinline__ short f2bf(float f) {
    uint32_t u = __builtin_bit_cast(uint32_t, f);
    uint32_t r = (u + 0x7fffu + ((u >> 16) & 1u)) >> 16;   // RNE
    return (short)r;
}
__device__ __forceinline__ int cvt2bf(float lo, float hi) {
    int r;
    asm("v_cvt_pk_bf16_f32 %0, %1, %2" : "=v"(r) : "v"(lo), "v"(hi));
    return r;
}
__device__ __forceinline__ short8 pk8(float4 a, float4 b) {
    intx4 t = {cvt2bf(a.x, a.y), cvt2bf(a.z, a.w), cvt2bf(b.x, b.y), cvt2bf(b.z, b.w)};
    return __builtin_bit_cast(short8, t);
}
// e = scg*(gate arg) already: sigmoid(e = -L2E*x), tanh(e = +2*L2E*x)
__device__ __forceinline__ float fsig2(float e) {
    return __builtin_amdgcn_rcpf(1.0f + __builtin_amdgcn_exp2f(e));
}
__device__ __forceinline__ float fth2(float e) {
    return 1.0f - 2.0f * __builtin_amdgcn_rcpf(1.0f + __builtin_amdgcn_exp2f(e));
}
__device__ __forceinline__ float ftanh(float x) {
    return 1.0f - 2.0f * __builtin_amdgcn_rcpf(1.0f + __builtin_amdgcn_exp2f(2.0f * L2E * x));
}
// barrier draining only LDS ops (NOT vmcnt -> producer global loads stay in flight)
__device__ __forceinline__ void sync_lds() {
    asm volatile("s_waitcnt lgkmcnt(0)\n\ts_barrier" ::: "memory");
}

__global__ __launch_bounds__(NTHR, 4) void lstm_persistent(
    const float* __restrict__ xin,
    const float* __restrict__ Wf, const float* __restrict__ Uf, const float* __restrict__ bfp,
    const float* __restrict__ Wi, const float* __restrict__ Ui, const float* __restrict__ bip,
    const float* __restrict__ Wc, const float* __restrict__ Uc, const float* __restrict__ bcp,
    const float* __restrict__ Wo, const float* __restrict__ Uo, const float* __restrict__ bop,
    float* __restrict__ out)
{
    __shared__ float Gx[2][16 * GXSTR];              // scg*(xW+b), gate-major rows
    __shared__ __align__(8) char A1[2][2 * A1STRB];  // h fp8-e4m3, dbuf by step parity

    const int tid  = threadIdx.x;
    const int wave = tid >> 6;     // 0..15
    const int lane = tid & 63;
    const int quad = lane >> 4;    // 0..3
    const int nlo  = lane & 15;
    const int blk  = blockIdx.x;

    const float* Wg[4] = {Wf, Wi, Wc, Wo};
    const float* Ug[4] = {Uf, Ui, Uc, Uo};
    const float* Bg[4] = {bfp, bip, bcp, bop};
    const float scg[4] = {-L2E, -L2E, 2.0f * L2E, -L2E};

    if (wave < 8) {
        // ======================= CONSUMER (8 thin waves) =======================
        __builtin_amdgcn_s_setprio(1);   // chain waves are latency-critical
        const int  prow = quad >> 1;        // batch row within block
        const bool wr   = (quad & 1) == 0;  // quads 1,3 mirror 0,2
        const int  u_s  = 16 * wave + nlo;  // this wave's u-column

        // recurrent scg*U as fp8 B-fragments (16 cols, 4 gates):
        // byte j of dword d -> k = quad*32 + 4d + j; col = nlo.
        intx8 bU8[4];
#pragma unroll
        for (int gt = 0; gt < 4; ++gt) {
            const float s = scg[gt];
#pragma unroll
            for (int d = 0; d < 8; ++d) {
                const int k0 = quad * 32 + d * 4;
                int pk = __builtin_amdgcn_cvt_pk_fp8_f32(
                    s * Ug[gt][(k0 + 0) * U_SZ + u_s], s * Ug[gt][(k0 + 1) * U_SZ + u_s], 0, 0);
                pk = __builtin_amdgcn_cvt_pk_fp8_f32(
                    s * Ug[gt][(k0 + 2) * U_SZ + u_s], s * Ug[gt][(k0 + 3) * U_SZ + u_s], pk, 1);
                bU8[gt][d] = pk;
            }
        }
        float c_st = 0.0f;

        // zero both h buffers (h(0)=0); consumer tids are 0..511
        for (int i = tid; i < 2 * 2 * A1STRB; i += 512) ((char*)A1)[i] = 0;
        __syncthreads();

        for (int g = 0; g < 128; ++g) {
            const float* GxR = &Gx[g & 1][0];
#pragma unroll
            for (int j = 0; j < 8; ++j) {
                // ---- reads first: h fragment (2x b128), gx (4x b32, gate-major) ----
                const char* ap = &A1[j & 1][(nlo >> 3) * A1STRB + quad * 32];
                intx4 alo = *(const intx4*)(ap);
                intx4 ahi = *(const intx4*)(ap + 16);
                const float* gr = &GxR[(2 * j + prow) * GXSTR + u_s];
                floatx4 gx = {gr[0], gr[U_SZ], gr[2 * U_SZ], gr[3 * U_SZ]};
                intx8 a8 = {alo.x, alo.y, alo.z, alo.w, ahi.x, ahi.y, ahi.z, ahi.w};

                // ---- 4 scaled fp8 MFMAs, C = gx (row quad*4+r is same batch
                //      for all r, so acc[gt][gt] = scg*hU_gt + gx[gt]) ----
                floatx4 acc[4];
#pragma unroll
                for (int gt = 0; gt < 4; ++gt)
                    acc[gt] = __builtin_amdgcn_mfma_scale_f32_16x16x128_f8f6f4(
                        a8, bU8[gt], gx, 0, 0, 0, 0x7f7f7f7f, 0, 0x7f7f7f7f);

                // ---- activations straight off the MFMA outputs ----
                float fg = fsig2(acc[0][0]);
                float ig = fsig2(acc[1][1]);
                float ct = fth2 (acc[2][2]);
                float og = fsig2(acc[3][3]);

                float c = fg * c_st + ig * ct;
                float h = og * ftanh(c);
                c_st = c;

                if (g == 127 && j == 7) {
                    if (wr) out[(size_t)(blk * ROWS + prow) * U_SZ + u_s] = h;
                } else if (wr) {
                    int pk = __builtin_amdgcn_cvt_pk_fp8_f32(h, h, 0, 0);
                    A1[(j & 1) ^ 1][prow * A1STRB + u_s] = (char)(pk & 0xff);
                }
                sync_lds();
            }
        }
    } else {
        // ======================= PRODUCER (8 waves) =======================
        // wave p owns u-subtile p x 4 gates = 4 N-tiles; 1 tile per odd step.
        const int p = wave - 8;
        const int brow  = nlo & 1;     // A-frag row m=nlo -> (t_off, brow)
        const int t_off = nlo >> 1;
        const int uc    = 16 * p + nlo;

        // bf16(scg*W) fragments for 4 tiles (one per gate), K=64 + scg*bias.
        short8 bWp[4][2];
        float  bwsc[4];
#pragma unroll
        for (int gt = 0; gt < 4; ++gt) {
            const float s = scg[gt];
            bwsc[gt] = s * Bg[gt][uc];
#pragma unroll
            for (int kt = 0; kt < 2; ++kt)
#pragma unroll
                for (int jj = 0; jj < 8; ++jj) {
                    int k = kt * 32 + quad * 8 + jj;
                    bWp[gt][kt][jj] = f2bf(s * Wg[gt][k * U_SZ + uc]);
                }
        }

        const float* xg = xin + ((size_t)(blk * ROWS + brow) * T_SZ) * D_SZ + quad * 8;

        // ---- prologue: xproj(0) -> Gx[0]; xa = x(1); xq = x(2) in flight ----
        float4 p0 = *(const float4*)(xg + (size_t)t_off * D_SZ + 0);
        float4 p1 = *(const float4*)(xg + (size_t)t_off * D_SZ + 4);
        float4 p2 = *(const float4*)(xg + (size_t)t_off * D_SZ + 32);
        float4 p3 = *(const float4*)(xg + (size_t)t_off * D_SZ + 36);
        float4 q0 = *(const float4*)(xg + (size_t)(8 + t_off) * D_SZ + 0);
        float4 q1 = *(const float4*)(xg + (size_t)(8 + t_off) * D_SZ + 4);
        float4 q2 = *(const float4*)(xg + (size_t)(8 + t_off) * D_SZ + 32);
        float4 q3 = *(const float4*)(xg + (size_t)(8 + t_off) * D_SZ + 36);

        short8 xa0 = pk8(p0, p1);
        short8 xa1 = pk8(p2, p3);
#pragma unroll
        for (int gt = 0; gt < 4; ++gt) {
            floatx4 acc = (floatx4){0.f, 0.f, 0.f, 0.f};
            acc = __builtin_amdgcn_mfma_f32_16x16x32_bf16(xa0, bWp[gt][0], acc, 0, 0, 0);
            acc = __builtin_amdgcn_mfma_f32_16x16x32_bf16(xa1, bWp[gt][1], acc, 0, 0, 0);
#pragma unroll
            for (int r = 0; r < 4; ++r)
                Gx[0][(quad * 4 + r) * GXSTR + gt * U_SZ + uc] = acc[r] + bwsc[gt];
        }
        // xa = x(1)
        xa0 = pk8(q0, q1);
        xa1 = pk8(q2, q3);
        // xq = x(2), in flight
        float4 xq0 = *(const float4*)(xg + (size_t)(16 + t_off) * D_SZ + 0);
        float4 xq1 = *(const float4*)(xg + (size_t)(16 + t_off) * D_SZ + 4);
        float4 xq2 = *(const float4*)(xg + (size_t)(16 + t_off) * D_SZ + 32);
        float4 xq3 = *(const float4*)(xg + (size_t)(16 + t_off) * D_SZ + 36);
        __syncthreads();

        short8 xn0 = xa0, xn1 = xa1;
        for (int g = 0; g < 128; ++g) {
            float* GxW = &Gx[(g + 1) & 1][0];
#pragma unroll
            for (int j = 0; j < 8; ++j) {
                if (j == 0 && g <= 125) {   // cvt xq -> x(g+2) frags
                    xn0 = pk8(xq0, xq1);
                    xn1 = pk8(xq2, xq3);
                }
                if (j == 2 && g <= 124) {   // issue loads of x(g+3)
                    const float* b = xg + (size_t)(8 * (g + 3) + t_off) * D_SZ;
                    xq0 = *(const float4*)(b + 0);
                    xq1 = *(const float4*)(b + 4);
                    xq2 = *(const float4*)(b + 32);
                    xq3 = *(const float4*)(b + 36);
                }
                if ((j & 1) && g < 127) {   // gate gt=j>>1 tile of xproj(g+1)
                    const int gt = j >> 1;
                    floatx4 acc = (floatx4){0.f, 0.f, 0.f, 0.f};
                    acc = __builtin_amdgcn_mfma_f32_16x16x32_bf16(xa0, bWp[gt][0], acc, 0, 0, 0);
                    acc = __builtin_amdgcn_mfma_f32_16x16x32_bf16(xa1, bWp[gt][1], acc, 0, 0, 0);
#pragma unroll
                    for (int r = 0; r < 4; ++r)
                        GxW[(quad * 4 + r) * GXSTR + gt * U_SZ + uc] = acc[r] + bwsc[gt];
                }
                sync_lds();
            }
            xa0 = xn0; xa1 = xn1;
        }
    }
}

extern "C" void kernel_launch(void* const* d_in, const int* in_sizes, int n_in,
                              void* d_out, int out_size, void* d_ws, size_t ws_size,
                              hipStream_t stream) {
    (void)in_sizes; (void)n_in; (void)d_ws; (void)ws_size; (void)out_size;
    const float* xin = (const float*)d_in[0];
    const float* Wf  = (const float*)d_in[1];
    const float* Uf  = (const float*)d_in[2];
    const float* bf  = (const float*)d_in[3];
    const float* Wi  = (const float*)d_in[4];
    const float* Ui  = (const float*)d_in[5];
    const float* bi  = (const float*)d_in[6];
    const float* Wc  = (const float*)d_in[7];
    const float* Uc  = (const float*)d_in[8];
    const float* bc  = (const float*)d_in[9];
    const float* Wo  = (const float*)d_in[10];
    const float* Uo  = (const float*)d_in[11];
    const float* bo  = (const float*)d_in[12];
    float* out = (float*)d_out;

    hipLaunchKernelGGL(lstm_persistent, dim3(NBLK), dim3(NTHR), 0, stream,
                       xin, Wf, Uf, bf, Wi, Ui, bi, Wc, Uc, bc, Wo, Uo, bo, out);
}